// Round 8
// baseline (651.591 us; speedup 1.0000x reference)
//
#include <hip/hip_runtime.h>
#include <hip/hip_bf16.h>

#define NEG_SLOPE 0.2f
#define LOG2E 1.4426950408889634f

typedef short short8 __attribute__((ext_vector_type(8)));
typedef float f32x4 __attribute__((ext_vector_type(4)));

__device__ __forceinline__ unsigned short f2bf(float f)
{
    union { __hip_bfloat16 b; unsigned short u; } v;
    v.b = __float2bfloat16(f);
    return v.u;
}

// ================= init: zero counters/barriers + pack W fragments =================
// W fragment order (per gemm_alpha_mfma): frag f = s*4+t, lane l, elem i:
// k = 32*s + 8*(l/16) + i,  n = 16*t + (l%16). Same (l/16,i)->k map as the
// A-side pack, so any HW k-permutation cancels.
__global__ __launch_bounds__(256) void init_kernel(
    const float* __restrict__ W1, const float* __restrict__ W2,
    unsigned short* __restrict__ wf1, unsigned short* __restrict__ wf2,
    int* __restrict__ cnt, int* __restrict__ bars, int N)
{
    const int tid = blockIdx.x * 256 + threadIdx.x;
    if (tid < 16) bars[tid] = 0;
    if (tid < 128 * 64) {
        int i = tid & 7, l = (tid >> 3) & 63, f = tid >> 9;
        int s = f >> 2, tt = f & 3;
        wf1[tid] = f2bf(W1[(32 * s + 8 * (l >> 4) + i) * 64 + (16 * tt + (l & 15))]);
    }
    if (tid < 64 * 64) {
        int i = tid & 7, l = (tid >> 3) & 63, f = tid >> 9;
        int s = f >> 2, tt = f & 3;
        wf2[tid] = f2bf(W2[(32 * s + 8 * (l >> 4) + i) * 64 + (16 * tt + (l & 15))]);
    }
    for (int n = tid; n < N; n += gridDim.x * 256) cnt[n] = 0;
}

// ================= fused CSR build (1 launch, grid barriers) =================
// Grid MUST be <= 256 blocks (co-resident on 256 CUs) for the barrier.
__device__ __forceinline__ void grid_bar(int* bar, int nb)
{
    __syncthreads();
    __threadfence();
    if (threadIdx.x == 0) {
        __hip_atomic_fetch_add(bar, 1, __ATOMIC_ACQ_REL, __HIP_MEMORY_SCOPE_AGENT);
        while (__hip_atomic_load(bar, __ATOMIC_ACQUIRE, __HIP_MEMORY_SCOPE_AGENT) < nb)
            __builtin_amdgcn_s_sleep(1);
    }
    __syncthreads();
    __threadfence();
}

// count degrees -> scan -> row_ptr/cur -> atomic scatter into col_idx.
__global__ __launch_bounds__(256) void csr_fused_kernel(
    const int* __restrict__ adj, int* __restrict__ cnt,
    int* __restrict__ row_ptr, int* __restrict__ cur,
    int* __restrict__ csum, int* __restrict__ bars,
    int* __restrict__ col_idx, int E, int N)
{
    const int t = threadIdx.x;
    const int b = blockIdx.x;
    const int NB = gridDim.x;            // 256
    const int ET = E + N;
    const int gsz = NB * 256;
    const int NC = (N + 255) >> 8;       // chunks of 256 (<=512 for N<=131072)
    __shared__ int s[512];

    // phase 1: degree count (self-loop for every node)
    for (int i = b * 256 + t; i < ET; i += gsz) {
        int d = (i < E) ? adj[E + i] : (i - E);
        atomicAdd(&cnt[d], 1);
    }
    grid_bar(&bars[0], NB);

    // phase 2: chunk-local exclusive scan; chunk totals -> csum
    for (int c = b; c < NC; c += NB) {
        int i = c * 256 + t;
        int v = (i < N) ? cnt[i] : 0;
        s[t] = v;
        __syncthreads();
        for (int off = 1; off < 256; off <<= 1) {
            int u = (t >= off) ? s[t - off] : 0;
            __syncthreads();
            s[t] += u;
            __syncthreads();
        }
        if (i < N) row_ptr[i] = s[t] - v;
        if (t == 255)
            __hip_atomic_store(&csum[c], s[255], __ATOMIC_RELEASE, __HIP_MEMORY_SCOPE_AGENT);
        __syncthreads();
    }
    grid_bar(&bars[1], NB);

    // phase 3: block 0 scans chunk totals (2 per thread, up to 512)
    if (b == 0) {
        int i1 = t + 256;
        int v0 = (t < NC) ? __hip_atomic_load(&csum[t], __ATOMIC_ACQUIRE, __HIP_MEMORY_SCOPE_AGENT) : 0;
        int v1 = (i1 < NC) ? __hip_atomic_load(&csum[i1], __ATOMIC_ACQUIRE, __HIP_MEMORY_SCOPE_AGENT) : 0;
        s[t] = v0; s[i1] = v1;
        __syncthreads();
        for (int off = 1; off < 512; off <<= 1) {
            int u0 = (t >= off) ? s[t - off] : 0;
            int u1 = (i1 >= off) ? s[i1 - off] : 0;
            __syncthreads();
            s[t] += u0; s[i1] += u1;
            __syncthreads();
        }
        int e0 = t ? s[t - 1] : 0;
        int e1 = s[i1 - 1];
        if (t < NC)  __hip_atomic_store(&csum[t],  e0, __ATOMIC_RELEASE, __HIP_MEMORY_SCOPE_AGENT);
        if (i1 < NC) __hip_atomic_store(&csum[i1], e1, __ATOMIC_RELEASE, __HIP_MEMORY_SCOPE_AGENT);
    }
    grid_bar(&bars[2], NB);

    // phase 4: add chunk offsets; publish cur
    for (int c = b; c < NC; c += NB) {
        int off = __hip_atomic_load(&csum[c], __ATOMIC_ACQUIRE, __HIP_MEMORY_SCOPE_AGENT);
        int i = c * 256 + t;
        if (i < N) {
            int rp = row_ptr[i] + off;
            row_ptr[i] = rp;
            __hip_atomic_store(&cur[i], rp, __ATOMIC_RELEASE, __HIP_MEMORY_SCOPE_AGENT);
            if (i == N - 1) row_ptr[N] = rp + cnt[i];
        }
    }
    grid_bar(&bars[3], NB);

    // phase 5: scatter (col_idx consumed by later kernels only)
    for (int i = b * 256 + t; i < ET; i += gsz) {
        int sn, d;
        if (i < E) { sn = adj[i]; d = adj[E + i]; }
        else       { sn = d = i - E; }
        int pos = atomicAdd(&cur[d], 1);
        col_idx[pos] = sn;
    }
}

// ================= dense pieces =================

// MFMA GEMM + alpha:  h = bf16(X @ W); as[n] = (h . a_src)*log2e; ad likewise.
// X split hi+lo bf16 (2 MFMAs/tile). as_/ad_ pre-scaled by log2e so the
// aggregate uses exp2 directly (leaky_relu is positively homogeneous).
template<int K>
__global__ __launch_bounds__(256) void gemm_alpha_mfma(
    const float* __restrict__ X, const unsigned short* __restrict__ wf,
    const float* __restrict__ a_src, const float* __restrict__ a_dst,
    __hip_bfloat16* __restrict__ h, float* __restrict__ as_, float* __restrict__ ad_,
    int N, int nChunks)
{
    constexpr int S = K / 32;
    const int t = threadIdx.x;
    const int wave = t >> 6, lane = t & 63;
    const int g = lane >> 4, c = lane & 15;

    short8 bf[S * 4];
#pragma unroll
    for (int f = 0; f < S * 4; ++f)
        bf[f] = *(const short8*)(wf + ((size_t)(f * 64 + lane)) * 8);

    float asr[4], adr[4];
#pragma unroll
    for (int tt = 0; tt < 4; ++tt) {
        asr[tt] = a_src[16 * tt + c];
        adr[tt] = a_dst[16 * tt + c];
    }

    for (int chunk = blockIdx.x; chunk < nChunks; chunk += gridDim.x) {
        const int r0 = chunk * 64 + wave * 16;
        const int arow = r0 + c;
        const bool rv = arow < N;
        const float* xr = X + (size_t)arow * K;

        f32x4 acc[4];
#pragma unroll
        for (int tt = 0; tt < 4; ++tt) acc[tt] = (f32x4){0.f, 0.f, 0.f, 0.f};

#pragma unroll
        for (int s = 0; s < S; ++s) {
            float4 x0 = make_float4(0.f, 0.f, 0.f, 0.f);
            float4 x1 = make_float4(0.f, 0.f, 0.f, 0.f);
            if (rv) {
                const float4* p = (const float4*)(xr + 32 * s + 8 * g);
                x0 = p[0]; x1 = p[1];
            }
            float xs[8] = {x0.x, x0.y, x0.z, x0.w, x1.x, x1.y, x1.z, x1.w};
            union { short8 v; unsigned u[4]; } ah, al;
#pragma unroll
            for (int p2 = 0; p2 < 4; ++p2) {
                unsigned u0 = __float_as_uint(xs[2 * p2]);
                unsigned u1 = __float_as_uint(xs[2 * p2 + 1]);
                ah.u[p2] = (u0 >> 16) | (u1 & 0xffff0000u);
                float h0 = __uint_as_float(u0 & 0xffff0000u);
                float h1 = __uint_as_float(u1 & 0xffff0000u);
                unsigned l0 = __float_as_uint(xs[2 * p2] - h0);
                unsigned l1 = __float_as_uint(xs[2 * p2 + 1] - h1);
                al.u[p2] = (l0 >> 16) | (l1 & 0xffff0000u);
            }
#pragma unroll
            for (int tt = 0; tt < 4; ++tt) {
                acc[tt] = __builtin_amdgcn_mfma_f32_16x16x32_bf16(
                    ah.v, bf[s * 4 + tt], acc[tt], 0, 0, 0);
                acc[tt] = __builtin_amdgcn_mfma_f32_16x16x32_bf16(
                    al.v, bf[s * 4 + tt], acc[tt], 0, 0, 0);
            }
        }

#pragma unroll
        for (int i = 0; i < 4; ++i) {
            const int ri = r0 + 4 * g + i;
            float va = 0.f, vd = 0.f;
#pragma unroll
            for (int tt = 0; tt < 4; ++tt) {
                float v = acc[tt][i];
                va += v * asr[tt];
                vd += v * adr[tt];
                if (ri < N) h[(size_t)ri * 64 + 16 * tt + c] = __float2bfloat16(v);
            }
#pragma unroll
            for (int off = 8; off >= 1; off >>= 1) {
                va += __shfl_xor(va, off, 16);
                vd += __shfl_xor(vd, off, 16);
            }
            if (c == 0 && ri < N) { as_[ri] = va * LOG2E; ad_[ri] = vd * LOG2E; }
        }
    }
}

// Fused softmax+aggregate: ONE 8-LANE SUB PER NODE (8 nodes per wave),
// natural node order (deg-sort removed: R5-R7 showed the agg is pinned at a
// random-gather throughput wall ~40us regardless of divergence/ILP, so the
// sort's 3 extra launches were pure overhead). 8-edge unrolled windows.
#define ACC8(u, p)                                                              \
    w = u.x; acc[0] += p * __uint_as_float(w << 16); acc[1] += p * __uint_as_float(w & 0xffff0000u); \
    w = u.y; acc[2] += p * __uint_as_float(w << 16); acc[3] += p * __uint_as_float(w & 0xffff0000u); \
    w = u.z; acc[4] += p * __uint_as_float(w << 16); acc[5] += p * __uint_as_float(w & 0xffff0000u); \
    w = u.w; acc[6] += p * __uint_as_float(w << 16); acc[7] += p * __uint_as_float(w & 0xffff0000u);

__global__ __launch_bounds__(256) void gat_aggregate_kernel(
    const int* __restrict__ row_ptr, const int* __restrict__ col_idx,
    const float* __restrict__ as_, const float* __restrict__ ad_,
    const __hip_bfloat16* __restrict__ h, const float* __restrict__ b,
    float* __restrict__ out, int N, int do_elu)
{
    const int wave = threadIdx.x >> 6, lane = threadIdx.x & 63;
    const int sub = lane >> 3, q = lane & 7;
    const int node = blockIdx.x * 32 + wave * 8 + sub;
    if (node >= N) return;
    const int beg = row_ptr[node], end = row_ptr[node + 1];
    const float ad = ad_[node];          // pre-scaled by log2e
    float acc[8] = {0.f, 0.f, 0.f, 0.f, 0.f, 0.f, 0.f, 0.f};
    float psum = 0.f;

    const char* cbp = (const char*)col_idx;
    const char* abp = (const char*)as_;
    const char* hbp = (const char*)h;
    const unsigned qb = (unsigned)q * 16u;
    unsigned w;

    int i = beg;
    unsigned co = (unsigned)beg * 4u;
    for (; i + 8 <= end; i += 8, co += 32u) {
        int s[8];
#pragma unroll
        for (int k = 0; k < 8; ++k) s[k] = *(const int*)(cbp + (co + 4u * k));
        float x[8];
#pragma unroll
        for (int k = 0; k < 8; ++k) x[k] = *(const float*)(abp + ((unsigned)s[k] << 2)) + ad;
        uint4 u[8];
#pragma unroll
        for (int k = 0; k < 8; ++k) u[k] = *(const uint4*)(hbp + (((unsigned)s[k] << 7) + qb));
#pragma unroll
        for (int k = 0; k < 8; ++k) {
            float xx = fmaxf(x[k], NEG_SLOPE * x[k]);
            float p = __builtin_amdgcn_exp2f(xx);
            psum += p;
            ACC8(u[k], p)
        }
    }
    for (; i < end; ++i, co += 4u) {
        int s0 = *(const int*)(cbp + co);
        float x0 = *(const float*)(abp + ((unsigned)s0 << 2)) + ad;
        uint4 u0 = *(const uint4*)(hbp + (((unsigned)s0 << 7) + qb));
        x0 = fmaxf(x0, NEG_SLOPE * x0);
        float p0 = __builtin_amdgcn_exp2f(x0);
        psum += p0;
        ACC8(u0, p0)
    }

    const float inv = 1.f / psum;
    const float* bq = b + q * 8;
    float4 b0 = *(const float4*)bq;
    float4 b1 = *(const float4*)(bq + 4);
    float v[8];
    v[0] = acc[0] * inv + b0.x; v[1] = acc[1] * inv + b0.y;
    v[2] = acc[2] * inv + b0.z; v[3] = acc[3] * inv + b0.w;
    v[4] = acc[4] * inv + b1.x; v[5] = acc[5] * inv + b1.y;
    v[6] = acc[6] * inv + b1.z; v[7] = acc[7] * inv + b1.w;
    if (do_elu) {
#pragma unroll
        for (int j = 0; j < 8; ++j)
            v[j] = v[j] > 0.f ? v[j] : (__expf(v[j]) - 1.f);
    }
    float* op = out + (size_t)node * 64 + q * 8;
    ((float4*)op)[0] = make_float4(v[0], v[1], v[2], v[3]);
    ((float4*)op)[1] = make_float4(v[4], v[5], v[6], v[7]);
}

// logits[n][c] = x[n]·cW[:,c] + cb[c]
__global__ __launch_bounds__(256) void classifier_kernel(
    const float* __restrict__ x, const float* __restrict__ cw,
    const float* __restrict__ cb, float* __restrict__ out, int N)
{
    int i = blockIdx.x * blockDim.x + threadIdx.x;
    if (i >= N * 16) return;
    int n = i >> 4, c = i & 15;
    const float4* xr = (const float4*)(x + (size_t)n * 64);
    float acc = cb[c];
#pragma unroll
    for (int j4 = 0; j4 < 16; ++j4) {
        float4 xv = xr[j4];
        acc += xv.x * cw[(j4 * 4 + 0) * 16 + c];
        acc += xv.y * cw[(j4 * 4 + 1) * 16 + c];
        acc += xv.z * cw[(j4 * 4 + 2) * 16 + c];
        acc += xv.w * cw[(j4 * 4 + 3) * 16 + c];
    }
    out[i] = acc;
}

extern "C" void kernel_launch(void* const* d_in, const int* in_sizes, int n_in,
                              void* d_out, int out_size, void* d_ws, size_t ws_size,
                              hipStream_t stream)
{
    const float* X    = (const float*)d_in[0];
    const int*   adj  = (const int*)d_in[1];
    const float* W1   = (const float*)d_in[2];
    const float* a_s1 = (const float*)d_in[3];
    const float* a_d1 = (const float*)d_in[4];
    const float* b1   = (const float*)d_in[5];
    const float* W2   = (const float*)d_in[6];
    const float* a_s2 = (const float*)d_in[7];
    const float* a_d2 = (const float*)d_in[8];
    const float* b2   = (const float*)d_in[9];
    const float* cW   = (const float*)d_in[10];
    const float* cb   = (const float*)d_in[11];

    const int N   = in_sizes[0] / 128;
    const int E   = in_sizes[1] / 2;
    const int ET  = E + N;

    __hip_bfloat16* A = (__hip_bfloat16*)d_ws;        // h (bf16), N*64
    float* B       = (float*)(A + (size_t)N * 64);    // layer1 x, N*64 f32
    float* asb     = B + (size_t)N * 64;              // N
    float* adb     = asb + N;                         // N
    int*   row_ptr = (int*)(adb + N);                 // N+1
    int*   col_idx = row_ptr + (N + 1);               // ET
    int*   cnt     = col_idx + ET;                    // N
    int*   cur     = cnt + N;                         // N
    int*   csum    = cur + N;                         // 512
    int*   bars    = csum + 512;                      // 16
    unsigned short* wf1 = (unsigned short*)(bars + 16);   // 128*64
    unsigned short* wf2 = wf1 + 128 * 64;                 // 64*64

    const int T = 256;
    const int aggBlocks  = (N + 31) / 32;
    const int nChunks    = (N + 63) / 64;
    const int gemmBlocks = nChunks < 512 ? nChunks : 512;

    // 1. init (zero cnt/bars + pack both W fragment buffers)
    init_kernel<<<256, T, 0, stream>>>(W1, W2, wf1, wf2, cnt, bars, N);
    // 2. fused CSR build (count -> scan -> scatter, grid barriers, 1 launch)
    csr_fused_kernel<<<256, T, 0, stream>>>(
        adj, cnt, row_ptr, cur, csum, bars, col_idx, E, N);

    // 3-4. layer 1
    gemm_alpha_mfma<128><<<gemmBlocks, T, 0, stream>>>(
        X, wf1, a_s1, a_d1, A, asb, adb, N, nChunks);
    gat_aggregate_kernel<<<aggBlocks, T, 0, stream>>>(
        row_ptr, col_idx, asb, adb, A, b1, B, N, 1);

    // 5-6. layer 2 (x written straight into d_out tail)
    float* out  = (float*)d_out;
    float* xout = out + (size_t)N * 16;
    gemm_alpha_mfma<64><<<gemmBlocks, T, 0, stream>>>(
        B, wf2, a_s2, a_d2, A, asb, adb, N, nChunks);
    gat_aggregate_kernel<<<aggBlocks, T, 0, stream>>>(
        row_ptr, col_idx, asb, adb, A, b2, xout, N, 0);

    // 7. classifier
    classifier_kernel<<<(N * 16 + T - 1) / T, T, 0, stream>>>(
        xout, cW, cb, out, N);
}

// Round 9
// 320.811 us; speedup vs baseline: 2.0311x; 2.0311x over previous
//
#include <hip/hip_runtime.h>
#include <hip/hip_bf16.h>

#define NEG_SLOPE 0.2f
#define LOG2E 1.4426950408889634f
#define BSH 9                    // 512 dst nodes per bucket
#define BW  (1 << BSH)
#define CH  4096                 // edges per partition round
#define PGRID 256                // workgroups for A0/A1

typedef short short8 __attribute__((ext_vector_type(8)));
typedef float f32x4 __attribute__((ext_vector_type(4)));

// ================= radix CSR build (no global atomics — R4-proven) =================

// A0: per-round bucket histogram. H[r*NBK + b] = #edges of round r in bucket b.
__global__ __launch_bounds__(256) void bucket_hist_kernel(
    const int* __restrict__ adj, int* __restrict__ H, int E, int N, int R, int NBK)
{
    __shared__ int hist[256];
    const int t = threadIdx.x;
    const int ET = E + N;
    for (int r = blockIdx.x; r < R; r += gridDim.x) {
        hist[t] = 0;
        __syncthreads();
        int base = r * CH;
        for (int i = 0; i < CH / 256; ++i) {
            int e = base + i * 256 + t;
            if (e >= ET) break;
            int d = (e < E) ? adj[E + e] : (e - E);
            atomicAdd(&hist[d >> BSH], 1);
        }
        __syncthreads();
        if (t < NBK) H[r * NBK + t] = hist[t];
        __syncthreads();
    }
}

// Per-bucket scan over rounds: S2[r][b] = within-bucket prefix, tot[b] = total.
__global__ __launch_bounds__(256) void scan_rounds_kernel(
    const int* __restrict__ H, int* __restrict__ S2, int* __restrict__ tot,
    int R, int NBK)
{
    __shared__ int part[256];
    const int b = blockIdx.x;
    const int t = threadIdx.x;
    const int C = (R + 255) / 256;
    int r0 = t * C, r1 = min(R, r0 + C);
    int s = 0;
    for (int r = r0; r < r1; ++r) s += H[r * NBK + b];
    part[t] = s;
    __syncthreads();
    for (int off = 1; off < 256; off <<= 1) {
        int v = (t >= off) ? part[t - off] : 0;
        __syncthreads();
        part[t] += v;
        __syncthreads();
    }
    int run = (t > 0) ? part[t - 1] : 0;
    for (int r = r0; r < r1; ++r) {
        int h = H[r * NBK + b];
        S2[r * NBK + b] = run;
        run += h;
    }
    if (t == 255) tot[b] = part[255];
}

// Exclusive scan of bucket totals -> base[b]. One block; NBK <= 256.
__global__ __launch_bounds__(256) void scan_tot_kernel(
    const int* __restrict__ tot, int* __restrict__ base, int NBK)
{
    __shared__ int s[256];
    int t = threadIdx.x;
    int v = (t < NBK) ? tot[t] : 0;
    s[t] = v;
    __syncthreads();
    for (int off = 1; off < 256; off <<= 1) {
        int u = (t >= off) ? s[t - off] : 0;
        __syncthreads();
        s[t] += u;
        __syncthreads();
    }
    if (t < NBK) base[t] = s[t] - v;
}

// A1: scatter edges into bucket-grouped pbuf at precomputed offsets.
__global__ __launch_bounds__(256) void partition_kernel(
    const int* __restrict__ adj, const int* __restrict__ S2,
    const int* __restrict__ base, int* __restrict__ pbuf,
    int E, int N, int R, int NBK)
{
    __shared__ int lcur[256];
    const int t = threadIdx.x;
    const int ET = E + N;
    for (int r = blockIdx.x; r < R; r += gridDim.x) {
        if (t < NBK) lcur[t] = base[t] + S2[r * NBK + t];
        __syncthreads();
        int b0 = r * CH;
        for (int i = 0; i < CH / 256; ++i) {
            int e = b0 + i * 256 + t;
            if (e >= ET) break;
            int s, d;
            if (e < E) { d = adj[E + e]; s = adj[e]; }
            else       { s = d = e - E; }
            int b = d >> BSH;
            int pos = atomicAdd(&lcur[b], 1);
            pbuf[pos] = (s << BSH) | (d & (BW - 1));
        }
        __syncthreads();
    }
}

// B: one WG per bucket -> row_ptr window + node-grouped col_idx (LDS atomics).
__global__ __launch_bounds__(256) void csr_build_kernel(
    const int* __restrict__ base, const int* __restrict__ tot,
    const int* __restrict__ pbuf,
    int* __restrict__ row_ptr, int* __restrict__ col_idx, int E, int N, int NBK)
{
    __shared__ int offA[BW];
    __shared__ int lcur[BW];
    const int b = blockIdx.x;
    const int t = threadIdx.x;
    const int node0 = b << BSH;
    const int nn = min(BW, N - node0);
    const int ET = E + N;
    const int segbeg = base[b];
    const int segend = segbeg + tot[b];

    offA[t] = 0; offA[t + 256] = 0;
    __syncthreads();
    for (int i = segbeg + t; i < segend; i += 256)
        atomicAdd(&offA[pbuf[i] & (BW - 1)], 1);
    __syncthreads();
    for (int off = 1; off < BW; off <<= 1) {
        int i1 = t + 256;
        int v0 = (t >= off) ? offA[t - off] : 0;
        int v1 = (i1 >= off) ? offA[i1 - off] : 0;
        __syncthreads();
        offA[t] += v0; offA[i1] += v1;
        __syncthreads();
    }
    if (t < nn) {
        int ex = t ? offA[t - 1] : 0;
        row_ptr[node0 + t] = segbeg + ex;
        lcur[t] = segbeg + ex;
    }
    int i2 = t + 256;
    if (i2 < nn) {
        int ex = offA[i2 - 1];
        row_ptr[node0 + i2] = segbeg + ex;
        lcur[i2] = segbeg + ex;
    }
    if (b == NBK - 1 && t == 0) row_ptr[N] = ET;
    __syncthreads();
    for (int i = segbeg + t; i < segend; i += 256) {
        int p = pbuf[i];
        int pos = atomicAdd(&lcur[p & (BW - 1)], 1);
        col_idx[pos] = p >> BSH;
    }
}

// ================= dense pieces =================

__device__ __forceinline__ unsigned short f2bf(float f)
{
    union { __hip_bfloat16 b; unsigned short u; } v;
    v.b = __float2bfloat16(f);
    return v.u;
}

// Pack BOTH W matrices into MFMA B-fragment order, one launch.
// frag f = s*4+t, lane l, elem i: k = 32s + 8*(l/16) + i, n = 16t + (l%16).
__global__ __launch_bounds__(256) void prep_wfrag2_kernel(
    const float* __restrict__ W1, const float* __restrict__ W2,
    unsigned short* __restrict__ wf1, unsigned short* __restrict__ wf2)
{
    int idx = blockIdx.x * 256 + threadIdx.x;
    if (idx < 128 * 64) {
        int i = idx & 7, l = (idx >> 3) & 63, f = idx >> 9;
        int s = f >> 2, tt = f & 3;
        wf1[idx] = f2bf(W1[(32 * s + 8 * (l >> 4) + i) * 64 + (16 * tt + (l & 15))]);
    }
    if (idx < 64 * 64) {
        int i = idx & 7, l = (idx >> 3) & 63, f = idx >> 9;
        int s = f >> 2, tt = f & 3;
        wf2[idx] = f2bf(W2[(32 * s + 8 * (l >> 4) + i) * 64 + (16 * tt + (l & 15))]);
    }
}

// MFMA GEMM + alpha:  h = bf16(X @ W); as[n] = (h . a_src)*log2e; ad likewise.
template<int K>
__global__ __launch_bounds__(256) void gemm_alpha_mfma(
    const float* __restrict__ X, const unsigned short* __restrict__ wf,
    const float* __restrict__ a_src, const float* __restrict__ a_dst,
    __hip_bfloat16* __restrict__ h, float* __restrict__ as_, float* __restrict__ ad_,
    int N, int nChunks)
{
    constexpr int S = K / 32;
    const int t = threadIdx.x;
    const int wave = t >> 6, lane = t & 63;
    const int g = lane >> 4, c = lane & 15;

    short8 bf[S * 4];
#pragma unroll
    for (int f = 0; f < S * 4; ++f)
        bf[f] = *(const short8*)(wf + ((size_t)(f * 64 + lane)) * 8);

    float asr[4], adr[4];
#pragma unroll
    for (int tt = 0; tt < 4; ++tt) {
        asr[tt] = a_src[16 * tt + c];
        adr[tt] = a_dst[16 * tt + c];
    }

    for (int chunk = blockIdx.x; chunk < nChunks; chunk += gridDim.x) {
        const int r0 = chunk * 64 + wave * 16;
        const int arow = r0 + c;
        const bool rv = arow < N;
        const float* xr = X + (size_t)arow * K;

        f32x4 acc[4];
#pragma unroll
        for (int tt = 0; tt < 4; ++tt) acc[tt] = (f32x4){0.f, 0.f, 0.f, 0.f};

#pragma unroll
        for (int s = 0; s < S; ++s) {
            float4 x0 = make_float4(0.f, 0.f, 0.f, 0.f);
            float4 x1 = make_float4(0.f, 0.f, 0.f, 0.f);
            if (rv) {
                const float4* p = (const float4*)(xr + 32 * s + 8 * g);
                x0 = p[0]; x1 = p[1];
            }
            float xs[8] = {x0.x, x0.y, x0.z, x0.w, x1.x, x1.y, x1.z, x1.w};
            union { short8 v; unsigned u[4]; } ah, al;
#pragma unroll
            for (int p2 = 0; p2 < 4; ++p2) {
                unsigned u0 = __float_as_uint(xs[2 * p2]);
                unsigned u1 = __float_as_uint(xs[2 * p2 + 1]);
                ah.u[p2] = (u0 >> 16) | (u1 & 0xffff0000u);
                float h0 = __uint_as_float(u0 & 0xffff0000u);
                float h1 = __uint_as_float(u1 & 0xffff0000u);
                unsigned l0 = __float_as_uint(xs[2 * p2] - h0);
                unsigned l1 = __float_as_uint(xs[2 * p2 + 1] - h1);
                al.u[p2] = (l0 >> 16) | (l1 & 0xffff0000u);
            }
#pragma unroll
            for (int tt = 0; tt < 4; ++tt) {
                acc[tt] = __builtin_amdgcn_mfma_f32_16x16x32_bf16(
                    ah.v, bf[s * 4 + tt], acc[tt], 0, 0, 0);
                acc[tt] = __builtin_amdgcn_mfma_f32_16x16x32_bf16(
                    al.v, bf[s * 4 + tt], acc[tt], 0, 0, 0);
            }
        }

#pragma unroll
        for (int i = 0; i < 4; ++i) {
            const int ri = r0 + 4 * g + i;
            float va = 0.f, vd = 0.f;
#pragma unroll
            for (int tt = 0; tt < 4; ++tt) {
                float v = acc[tt][i];
                va += v * asr[tt];
                vd += v * adr[tt];
                if (ri < N) h[(size_t)ri * 64 + 16 * tt + c] = __float2bfloat16(v);
            }
#pragma unroll
            for (int off = 8; off >= 1; off >>= 1) {
                va += __shfl_xor(va, off, 16);
                vd += __shfl_xor(vd, off, 16);
            }
            if (c == 0 && ri < N) { as_[ri] = va * LOG2E; ad_[ri] = vd * LOG2E; }
        }
    }
}

// Fused softmax+aggregate: ONE 8-LANE SUB PER NODE (8 nodes/wave), natural
// order, 8-edge unrolled windows (R4/R7/R8-proven loop, ~gather-throughput
// bound at ~40us). Optional fused classifier epilogue (layer 2): the x-row
// is already in the sub's registers, so logits cost 128 L1-hit FMAs/lane +
// a 3-round butterfly — hides under the ~20% VALUBusy latency slack, and
// kills the separate classifier kernel's 25.6MB re-read + launch.
#define ACC8(u, p)                                                              \
    w = u.x; acc[0] += p * __uint_as_float(w << 16); acc[1] += p * __uint_as_float(w & 0xffff0000u); \
    w = u.y; acc[2] += p * __uint_as_float(w << 16); acc[3] += p * __uint_as_float(w & 0xffff0000u); \
    w = u.z; acc[4] += p * __uint_as_float(w << 16); acc[5] += p * __uint_as_float(w & 0xffff0000u); \
    w = u.w; acc[6] += p * __uint_as_float(w << 16); acc[7] += p * __uint_as_float(w & 0xffff0000u);

__global__ __launch_bounds__(256) void gat_aggregate_kernel(
    const int* __restrict__ row_ptr, const int* __restrict__ col_idx,
    const float* __restrict__ as_, const float* __restrict__ ad_,
    const __hip_bfloat16* __restrict__ h, const float* __restrict__ b,
    float* __restrict__ out, int N, int do_elu,
    const float* __restrict__ cw, const float* __restrict__ cb,
    float* __restrict__ logits)
{
    const int wave = threadIdx.x >> 6, lane = threadIdx.x & 63;
    const int sub = lane >> 3, q = lane & 7;
    const int node = blockIdx.x * 32 + wave * 8 + sub;
    if (node >= N) return;
    const int beg = row_ptr[node], end = row_ptr[node + 1];
    const float ad = ad_[node];          // pre-scaled by log2e
    float acc[8] = {0.f, 0.f, 0.f, 0.f, 0.f, 0.f, 0.f, 0.f};
    float psum = 0.f;

    const char* cbp = (const char*)col_idx;
    const char* abp = (const char*)as_;
    const char* hbp = (const char*)h;
    const unsigned qb = (unsigned)q * 16u;
    unsigned w;

    int i = beg;
    unsigned co = (unsigned)beg * 4u;
    for (; i + 8 <= end; i += 8, co += 32u) {
        int s[8];
#pragma unroll
        for (int k = 0; k < 8; ++k) s[k] = *(const int*)(cbp + (co + 4u * k));
        float x[8];
#pragma unroll
        for (int k = 0; k < 8; ++k) x[k] = *(const float*)(abp + ((unsigned)s[k] << 2)) + ad;
        uint4 u[8];
#pragma unroll
        for (int k = 0; k < 8; ++k) u[k] = *(const uint4*)(hbp + (((unsigned)s[k] << 7) + qb));
#pragma unroll
        for (int k = 0; k < 8; ++k) {
            float xx = fmaxf(x[k], NEG_SLOPE * x[k]);
            float p = __builtin_amdgcn_exp2f(xx);
            psum += p;
            ACC8(u[k], p)
        }
    }
    for (; i < end; ++i, co += 4u) {
        int s0 = *(const int*)(cbp + co);
        float x0 = *(const float*)(abp + ((unsigned)s0 << 2)) + ad;
        uint4 u0 = *(const uint4*)(hbp + (((unsigned)s0 << 7) + qb));
        x0 = fmaxf(x0, NEG_SLOPE * x0);
        float p0 = __builtin_amdgcn_exp2f(x0);
        psum += p0;
        ACC8(u0, p0)
    }

    const float inv = 1.f / psum;
    const float* bq = b + q * 8;
    float4 b0 = *(const float4*)bq;
    float4 b1 = *(const float4*)(bq + 4);
    float v[8];
    v[0] = acc[0] * inv + b0.x; v[1] = acc[1] * inv + b0.y;
    v[2] = acc[2] * inv + b0.z; v[3] = acc[3] * inv + b0.w;
    v[4] = acc[4] * inv + b1.x; v[5] = acc[5] * inv + b1.y;
    v[6] = acc[6] * inv + b1.z; v[7] = acc[7] * inv + b1.w;
    if (do_elu) {
#pragma unroll
        for (int j = 0; j < 8; ++j)
            v[j] = v[j] > 0.f ? v[j] : (__expf(v[j]) - 1.f);
    }
    float* op = out + (size_t)node * 64 + q * 8;
    ((float4*)op)[0] = make_float4(v[0], v[1], v[2], v[3]);
    ((float4*)op)[1] = make_float4(v[4], v[5], v[6], v[7]);

    if (cw) {
        // fused classifier: lane q holds dims q*8..q*8+7 of x in v[]
        float lg[16];
#pragma unroll
        for (int c = 0; c < 16; ++c) lg[c] = 0.f;
#pragma unroll
        for (int k = 0; k < 8; ++k) {
            const float4* cwr = (const float4*)(cw + (q * 8 + k) * 16);
            float xv = v[k];
            float4 c0 = cwr[0], c1 = cwr[1], c2 = cwr[2], c3 = cwr[3];
            lg[0] += xv * c0.x; lg[1] += xv * c0.y; lg[2] += xv * c0.z; lg[3] += xv * c0.w;
            lg[4] += xv * c1.x; lg[5] += xv * c1.y; lg[6] += xv * c1.z; lg[7] += xv * c1.w;
            lg[8] += xv * c2.x; lg[9] += xv * c2.y; lg[10] += xv * c2.z; lg[11] += xv * c2.w;
            lg[12] += xv * c3.x; lg[13] += xv * c3.y; lg[14] += xv * c3.z; lg[15] += xv * c3.w;
        }
        // butterfly over the 8 lanes of this sub (lanes sub*8 .. sub*8+7)
#pragma unroll
        for (int off = 1; off < 8; off <<= 1) {
#pragma unroll
            for (int c = 0; c < 16; ++c) lg[c] += __shfl_xor(lg[c], off, 64);
        }
        // lane q writes classes 2q, 2q+1
        float2 o;
        o.x = lg[2 * q] + cb[2 * q];
        o.y = lg[2 * q + 1] + cb[2 * q + 1];
        *(float2*)(logits + (size_t)node * 16 + 2 * q) = o;
    }
}

extern "C" void kernel_launch(void* const* d_in, const int* in_sizes, int n_in,
                              void* d_out, int out_size, void* d_ws, size_t ws_size,
                              hipStream_t stream)
{
    const float* X    = (const float*)d_in[0];
    const int*   adj  = (const int*)d_in[1];
    const float* W1   = (const float*)d_in[2];
    const float* a_s1 = (const float*)d_in[3];
    const float* a_d1 = (const float*)d_in[4];
    const float* b1   = (const float*)d_in[5];
    const float* W2   = (const float*)d_in[6];
    const float* a_s2 = (const float*)d_in[7];
    const float* a_d2 = (const float*)d_in[8];
    const float* b2   = (const float*)d_in[9];
    const float* cW   = (const float*)d_in[10];
    const float* cb   = (const float*)d_in[11];

    const int N   = in_sizes[0] / 128;
    const int E   = in_sizes[1] / 2;
    const int ET  = E + N;
    const int R   = (ET + CH - 1) / CH;           // partition rounds
    const int NBK = (N + BW - 1) >> BSH;          // buckets (<=256)

    __hip_bfloat16* A = (__hip_bfloat16*)d_ws;        // h (bf16), N*64
    float* B       = (float*)(A + (size_t)N * 64);    // layer1 x, N*64 f32
    float* asb     = B + (size_t)N * 64;              // N
    float* adb     = asb + N;                         // N
    int*   row_ptr = (int*)(adb + N);                 // N+1
    int*   col_idx = row_ptr + (N + 1);               // ET
    int*   pbuf    = col_idx + ET;                    // ET
    int*   H       = pbuf + ET;                       // R*NBK
    int*   S2      = H + R * NBK;                     // R*NBK
    int*   tot     = S2 + R * NBK;                    // NBK
    int*   base    = tot + NBK;                       // NBK

    // W fragment buffers alias pbuf (dead after csr_build; prep runs after it)
    uintptr_t wp = ((uintptr_t)pbuf + 15) & ~(uintptr_t)15;
    unsigned short* wf1 = (unsigned short*)wp;        // 128*64 ushort = 16KB
    unsigned short* wf2 = wf1 + 128 * 64;             // 64*64 ushort = 8KB

    const int T = 256;
    const int aggBlocks  = (N + 31) / 32;
    const int nChunks    = (N + 63) / 64;
    const int gemmBlocks = nChunks < 512 ? nChunks : 512;

    // ---- radix CSR build (5 launches, LDS atomics only — R4-proven) ----
    bucket_hist_kernel<<<PGRID, T, 0, stream>>>(adj, H, E, N, R, NBK);
    scan_rounds_kernel<<<NBK, T, 0, stream>>>(H, S2, tot, R, NBK);
    scan_tot_kernel<<<1, T, 0, stream>>>(tot, base, NBK);
    partition_kernel<<<PGRID, T, 0, stream>>>(adj, S2, base, pbuf, E, N, R, NBK);
    csr_build_kernel<<<NBK, T, 0, stream>>>(base, tot, pbuf, row_ptr, col_idx, E, N, NBK);

    // ---- pack both W fragment buffers (1 launch; pbuf dead now) ----
    prep_wfrag2_kernel<<<(128 * 64 + 255) / 256, T, 0, stream>>>(W1, W2, wf1, wf2);

    // ---- layer 1 ----
    gemm_alpha_mfma<128><<<gemmBlocks, T, 0, stream>>>(
        X, wf1, a_s1, a_d1, A, asb, adb, N, nChunks);
    gat_aggregate_kernel<<<aggBlocks, T, 0, stream>>>(
        row_ptr, col_idx, asb, adb, A, b1, B, N, 1, nullptr, nullptr, nullptr);

    // ---- layer 2 + fused classifier (x into d_out tail, logits into d_out) ----
    float* out  = (float*)d_out;
    float* xout = out + (size_t)N * 16;
    gemm_alpha_mfma<64><<<gemmBlocks, T, 0, stream>>>(
        B, wf2, a_s2, a_d2, A, asb, adb, N, nChunks);
    gat_aggregate_kernel<<<aggBlocks, T, 0, stream>>>(
        row_ptr, col_idx, asb, adb, A, b2, xout, N, 0, cW, cb, out);
}

// Round 10
// 308.651 us; speedup vs baseline: 2.1111x; 1.0394x over previous
//
#include <hip/hip_runtime.h>
#include <hip/hip_bf16.h>

#define NEG_SLOPE 0.2f
#define LOG2E 1.4426950408889634f
#define BSH 9                    // 512 dst nodes per bucket
#define BW  (1 << BSH)
#define CH  4096                 // edges per partition round
#define PGRID 256                // workgroups for A0/A1

typedef short short8 __attribute__((ext_vector_type(8)));
typedef float f32x4 __attribute__((ext_vector_type(4)));

// ================= radix CSR build (no global atomics — R4-proven) =================

// A0: per-round bucket histogram. H[r*NBK + b] = #edges of round r in bucket b.
__global__ __launch_bounds__(256) void bucket_hist_kernel(
    const int* __restrict__ adj, int* __restrict__ H, int E, int N, int R, int NBK)
{
    __shared__ int hist[256];
    const int t = threadIdx.x;
    const int ET = E + N;
    for (int r = blockIdx.x; r < R; r += gridDim.x) {
        hist[t] = 0;
        __syncthreads();
        int base = r * CH;
        for (int i = 0; i < CH / 256; ++i) {
            int e = base + i * 256 + t;
            if (e >= ET) break;
            int d = (e < E) ? adj[E + e] : (e - E);
            atomicAdd(&hist[d >> BSH], 1);
        }
        __syncthreads();
        if (t < NBK) H[r * NBK + t] = hist[t];
        __syncthreads();
    }
}

// Per-bucket scan over rounds: S2[r][b] = within-bucket prefix, tot[b] = total.
__global__ __launch_bounds__(256) void scan_rounds_kernel(
    const int* __restrict__ H, int* __restrict__ S2, int* __restrict__ tot,
    int R, int NBK)
{
    __shared__ int part[256];
    const int b = blockIdx.x;
    const int t = threadIdx.x;
    const int C = (R + 255) / 256;
    int r0 = t * C, r1 = min(R, r0 + C);
    int s = 0;
    for (int r = r0; r < r1; ++r) s += H[r * NBK + b];
    part[t] = s;
    __syncthreads();
    for (int off = 1; off < 256; off <<= 1) {
        int v = (t >= off) ? part[t - off] : 0;
        __syncthreads();
        part[t] += v;
        __syncthreads();
    }
    int run = (t > 0) ? part[t - 1] : 0;
    for (int r = r0; r < r1; ++r) {
        int h = H[r * NBK + b];
        S2[r * NBK + b] = run;
        run += h;
    }
    if (t == 255) tot[b] = part[255];
}

// Exclusive scan of bucket totals -> base[b]. One block; NBK <= 256.
__global__ __launch_bounds__(256) void scan_tot_kernel(
    const int* __restrict__ tot, int* __restrict__ base, int NBK)
{
    __shared__ int s[256];
    int t = threadIdx.x;
    int v = (t < NBK) ? tot[t] : 0;
    s[t] = v;
    __syncthreads();
    for (int off = 1; off < 256; off <<= 1) {
        int u = (t >= off) ? s[t - off] : 0;
        __syncthreads();
        s[t] += u;
        __syncthreads();
    }
    if (t < NBK) base[t] = s[t] - v;
}

// A1: scatter edges into bucket-grouped pbuf at precomputed offsets.
__global__ __launch_bounds__(256) void partition_kernel(
    const int* __restrict__ adj, const int* __restrict__ S2,
    const int* __restrict__ base, int* __restrict__ pbuf,
    int E, int N, int R, int NBK)
{
    __shared__ int lcur[256];
    const int t = threadIdx.x;
    const int ET = E + N;
    for (int r = blockIdx.x; r < R; r += gridDim.x) {
        if (t < NBK) lcur[t] = base[t] + S2[r * NBK + t];
        __syncthreads();
        int b0 = r * CH;
        for (int i = 0; i < CH / 256; ++i) {
            int e = b0 + i * 256 + t;
            if (e >= ET) break;
            int s, d;
            if (e < E) { d = adj[E + e]; s = adj[e]; }
            else       { s = d = e - E; }
            int b = d >> BSH;
            int pos = atomicAdd(&lcur[b], 1);
            pbuf[pos] = (s << BSH) | (d & (BW - 1));
        }
        __syncthreads();
    }
}

// B: one WG per bucket -> row_ptr window + node-grouped col_idx (LDS atomics).
__global__ __launch_bounds__(256) void csr_build_kernel(
    const int* __restrict__ base, const int* __restrict__ tot,
    const int* __restrict__ pbuf,
    int* __restrict__ row_ptr, int* __restrict__ col_idx, int E, int N, int NBK)
{
    __shared__ int offA[BW];
    __shared__ int lcur[BW];
    const int b = blockIdx.x;
    const int t = threadIdx.x;
    const int node0 = b << BSH;
    const int nn = min(BW, N - node0);
    const int ET = E + N;
    const int segbeg = base[b];
    const int segend = segbeg + tot[b];

    offA[t] = 0; offA[t + 256] = 0;
    __syncthreads();
    for (int i = segbeg + t; i < segend; i += 256)
        atomicAdd(&offA[pbuf[i] & (BW - 1)], 1);
    __syncthreads();
    for (int off = 1; off < BW; off <<= 1) {
        int i1 = t + 256;
        int v0 = (t >= off) ? offA[t - off] : 0;
        int v1 = (i1 >= off) ? offA[i1 - off] : 0;
        __syncthreads();
        offA[t] += v0; offA[i1] += v1;
        __syncthreads();
    }
    if (t < nn) {
        int ex = t ? offA[t - 1] : 0;
        row_ptr[node0 + t] = segbeg + ex;
        lcur[t] = segbeg + ex;
    }
    int i2 = t + 256;
    if (i2 < nn) {
        int ex = offA[i2 - 1];
        row_ptr[node0 + i2] = segbeg + ex;
        lcur[i2] = segbeg + ex;
    }
    if (b == NBK - 1 && t == 0) row_ptr[N] = ET;
    __syncthreads();
    for (int i = segbeg + t; i < segend; i += 256) {
        int p = pbuf[i];
        int pos = atomicAdd(&lcur[p & (BW - 1)], 1);
        col_idx[pos] = p >> BSH;
    }
}

// ================= dense pieces =================

__device__ __forceinline__ unsigned short f2bf(float f)
{
    union { __hip_bfloat16 b; unsigned short u; } v;
    v.b = __float2bfloat16(f);
    return v.u;
}

// Pack BOTH W matrices into MFMA B-fragment order, one launch.
// frag f = s*4+t, lane l, elem i: k = 32s + 8*(l/16) + i, n = 16t + (l%16).
__global__ __launch_bounds__(256) void prep_wfrag2_kernel(
    const float* __restrict__ W1, const float* __restrict__ W2,
    unsigned short* __restrict__ wf1, unsigned short* __restrict__ wf2)
{
    int idx = blockIdx.x * 256 + threadIdx.x;
    if (idx < 128 * 64) {
        int i = idx & 7, l = (idx >> 3) & 63, f = idx >> 9;
        int s = f >> 2, tt = f & 3;
        wf1[idx] = f2bf(W1[(32 * s + 8 * (l >> 4) + i) * 64 + (16 * tt + (l & 15))]);
    }
    if (idx < 64 * 64) {
        int i = idx & 7, l = (idx >> 3) & 63, f = idx >> 9;
        int s = f >> 2, tt = f & 3;
        wf2[idx] = f2bf(W2[(32 * s + 8 * (l >> 4) + i) * 64 + (16 * tt + (l & 15))]);
    }
}

// MFMA GEMM + alpha:  h = bf16(X @ W); as[n] = (h . a_src)*log2e; ad likewise.
template<int K>
__global__ __launch_bounds__(256) void gemm_alpha_mfma(
    const float* __restrict__ X, const unsigned short* __restrict__ wf,
    const float* __restrict__ a_src, const float* __restrict__ a_dst,
    __hip_bfloat16* __restrict__ h, float* __restrict__ as_, float* __restrict__ ad_,
    int N, int nChunks)
{
    constexpr int S = K / 32;
    const int t = threadIdx.x;
    const int wave = t >> 6, lane = t & 63;
    const int g = lane >> 4, c = lane & 15;

    short8 bf[S * 4];
#pragma unroll
    for (int f = 0; f < S * 4; ++f)
        bf[f] = *(const short8*)(wf + ((size_t)(f * 64 + lane)) * 8);

    float asr[4], adr[4];
#pragma unroll
    for (int tt = 0; tt < 4; ++tt) {
        asr[tt] = a_src[16 * tt + c];
        adr[tt] = a_dst[16 * tt + c];
    }

    for (int chunk = blockIdx.x; chunk < nChunks; chunk += gridDim.x) {
        const int r0 = chunk * 64 + wave * 16;
        const int arow = r0 + c;
        const bool rv = arow < N;
        const float* xr = X + (size_t)arow * K;

        f32x4 acc[4];
#pragma unroll
        for (int tt = 0; tt < 4; ++tt) acc[tt] = (f32x4){0.f, 0.f, 0.f, 0.f};

#pragma unroll
        for (int s = 0; s < S; ++s) {
            float4 x0 = make_float4(0.f, 0.f, 0.f, 0.f);
            float4 x1 = make_float4(0.f, 0.f, 0.f, 0.f);
            if (rv) {
                const float4* p = (const float4*)(xr + 32 * s + 8 * g);
                x0 = p[0]; x1 = p[1];
            }
            float xs[8] = {x0.x, x0.y, x0.z, x0.w, x1.x, x1.y, x1.z, x1.w};
            union { short8 v; unsigned u[4]; } ah, al;
#pragma unroll
            for (int p2 = 0; p2 < 4; ++p2) {
                unsigned u0 = __float_as_uint(xs[2 * p2]);
                unsigned u1 = __float_as_uint(xs[2 * p2 + 1]);
                ah.u[p2] = (u0 >> 16) | (u1 & 0xffff0000u);
                float h0 = __uint_as_float(u0 & 0xffff0000u);
                float h1 = __uint_as_float(u1 & 0xffff0000u);
                unsigned l0 = __float_as_uint(xs[2 * p2] - h0);
                unsigned l1 = __float_as_uint(xs[2 * p2 + 1] - h1);
                al.u[p2] = (l0 >> 16) | (l1 & 0xffff0000u);
            }
#pragma unroll
            for (int tt = 0; tt < 4; ++tt) {
                acc[tt] = __builtin_amdgcn_mfma_f32_16x16x32_bf16(
                    ah.v, bf[s * 4 + tt], acc[tt], 0, 0, 0);
                acc[tt] = __builtin_amdgcn_mfma_f32_16x16x32_bf16(
                    al.v, bf[s * 4 + tt], acc[tt], 0, 0, 0);
            }
        }

#pragma unroll
        for (int i = 0; i < 4; ++i) {
            const int ri = r0 + 4 * g + i;
            float va = 0.f, vd = 0.f;
#pragma unroll
            for (int tt = 0; tt < 4; ++tt) {
                float v = acc[tt][i];
                va += v * asr[tt];
                vd += v * adr[tt];
                if (ri < N) h[(size_t)ri * 64 + 16 * tt + c] = __float2bfloat16(v);
            }
#pragma unroll
            for (int off = 8; off >= 1; off >>= 1) {
                va += __shfl_xor(va, off, 16);
                vd += __shfl_xor(vd, off, 16);
            }
            if (c == 0 && ri < N) { as_[ri] = va * LOG2E; ad_[ri] = vd * LOG2E; }
        }
    }
}

// Fused softmax+aggregate: ONE 8-LANE SUB PER NODE (8 nodes/wave), natural
// order, 2-EDGE windows (R4-measured config; the 8-edge window regresses 2x
// in natural order — R9 post-mortem — because tail cost is max_i(d_i mod 8)
// serial masked iterations; with 2-edge windows the tail is <=1 window).
// Optional fused classifier epilogue (layer 2): x-row already in registers,
// logits = 128 L1-hit FMAs/lane + 3-round butterfly, hides under gather
// latency; kills the classifier kernel's 25.6MB re-read + launch.
#define ACC8(u, p)                                                              \
    w = u.x; acc[0] += p * __uint_as_float(w << 16); acc[1] += p * __uint_as_float(w & 0xffff0000u); \
    w = u.y; acc[2] += p * __uint_as_float(w << 16); acc[3] += p * __uint_as_float(w & 0xffff0000u); \
    w = u.z; acc[4] += p * __uint_as_float(w << 16); acc[5] += p * __uint_as_float(w & 0xffff0000u); \
    w = u.w; acc[6] += p * __uint_as_float(w << 16); acc[7] += p * __uint_as_float(w & 0xffff0000u);

__global__ __launch_bounds__(256) void gat_aggregate_kernel(
    const int* __restrict__ row_ptr, const int* __restrict__ col_idx,
    const float* __restrict__ as_, const float* __restrict__ ad_,
    const __hip_bfloat16* __restrict__ h, const float* __restrict__ b,
    float* __restrict__ out, int N, int do_elu,
    const float* __restrict__ cw, const float* __restrict__ cb,
    float* __restrict__ logits)
{
    const int wave = threadIdx.x >> 6, lane = threadIdx.x & 63;
    const int sub = lane >> 3, q = lane & 7;
    const int node = blockIdx.x * 32 + wave * 8 + sub;
    if (node >= N) return;
    const int beg = row_ptr[node], end = row_ptr[node + 1];
    const float ad = ad_[node];          // pre-scaled by log2e
    float acc[8] = {0.f, 0.f, 0.f, 0.f, 0.f, 0.f, 0.f, 0.f};
    float psum = 0.f;

    const char* cbp = (const char*)col_idx;
    const char* abp = (const char*)as_;
    const char* hbp = (const char*)h;
    const unsigned qb = (unsigned)q * 16u;
    unsigned w;

    unsigned co = (unsigned)beg * 4u;
    for (int i = beg; i < end; i += 2, co += 8u) {
        const bool v1 = (i + 1) < end;
        int s0 = *(const int*)(cbp + co);
        int s1 = *(const int*)(cbp + (v1 ? co + 4u : co));
        float x0 = *(const float*)(abp + ((unsigned)s0 << 2)) + ad;
        float x1 = *(const float*)(abp + ((unsigned)s1 << 2)) + ad;
        uint4 u0 = *(const uint4*)(hbp + (((unsigned)s0 << 7) + qb));
        uint4 u1 = *(const uint4*)(hbp + (((unsigned)s1 << 7) + qb));
        x0 = fmaxf(x0, NEG_SLOPE * x0);
        x1 = fmaxf(x1, NEG_SLOPE * x1);
        float p0 = __builtin_amdgcn_exp2f(x0);
        float p1 = v1 ? __builtin_amdgcn_exp2f(x1) : 0.f;
        psum += p0 + p1;
        ACC8(u0, p0)
        ACC8(u1, p1)
    }

    const float inv = 1.f / psum;
    const float* bq = b + q * 8;
    float4 b0 = *(const float4*)bq;
    float4 b1 = *(const float4*)(bq + 4);
    float v[8];
    v[0] = acc[0] * inv + b0.x; v[1] = acc[1] * inv + b0.y;
    v[2] = acc[2] * inv + b0.z; v[3] = acc[3] * inv + b0.w;
    v[4] = acc[4] * inv + b1.x; v[5] = acc[5] * inv + b1.y;
    v[6] = acc[6] * inv + b1.z; v[7] = acc[7] * inv + b1.w;
    if (do_elu) {
#pragma unroll
        for (int j = 0; j < 8; ++j)
            v[j] = v[j] > 0.f ? v[j] : (__expf(v[j]) - 1.f);
    }
    float* op = out + (size_t)node * 64 + q * 8;
    ((float4*)op)[0] = make_float4(v[0], v[1], v[2], v[3]);
    ((float4*)op)[1] = make_float4(v[4], v[5], v[6], v[7]);

    if (cw) {
        // fused classifier: lane q holds dims q*8..q*8+7 of x in v[]
        float lg[16];
#pragma unroll
        for (int c = 0; c < 16; ++c) lg[c] = 0.f;
#pragma unroll
        for (int k = 0; k < 8; ++k) {
            const float4* cwr = (const float4*)(cw + (q * 8 + k) * 16);
            float xv = v[k];
            float4 c0 = cwr[0], c1 = cwr[1], c2 = cwr[2], c3 = cwr[3];
            lg[0] += xv * c0.x; lg[1] += xv * c0.y; lg[2] += xv * c0.z; lg[3] += xv * c0.w;
            lg[4] += xv * c1.x; lg[5] += xv * c1.y; lg[6] += xv * c1.z; lg[7] += xv * c1.w;
            lg[8] += xv * c2.x; lg[9] += xv * c2.y; lg[10] += xv * c2.z; lg[11] += xv * c2.w;
            lg[12] += xv * c3.x; lg[13] += xv * c3.y; lg[14] += xv * c3.z; lg[15] += xv * c3.w;
        }
        // butterfly over the 8 lanes of this sub
#pragma unroll
        for (int off = 1; off < 8; off <<= 1) {
#pragma unroll
            for (int c = 0; c < 16; ++c) lg[c] += __shfl_xor(lg[c], off, 64);
        }
        // lane q writes classes 2q, 2q+1
        float2 o;
        o.x = lg[2 * q] + cb[2 * q];
        o.y = lg[2 * q + 1] + cb[2 * q + 1];
        *(float2*)(logits + (size_t)node * 16 + 2 * q) = o;
    }
}

extern "C" void kernel_launch(void* const* d_in, const int* in_sizes, int n_in,
                              void* d_out, int out_size, void* d_ws, size_t ws_size,
                              hipStream_t stream)
{
    const float* X    = (const float*)d_in[0];
    const int*   adj  = (const int*)d_in[1];
    const float* W1   = (const float*)d_in[2];
    const float* a_s1 = (const float*)d_in[3];
    const float* a_d1 = (const float*)d_in[4];
    const float* b1   = (const float*)d_in[5];
    const float* W2   = (const float*)d_in[6];
    const float* a_s2 = (const float*)d_in[7];
    const float* a_d2 = (const float*)d_in[8];
    const float* b2   = (const float*)d_in[9];
    const float* cW   = (const float*)d_in[10];
    const float* cb   = (const float*)d_in[11];

    const int N   = in_sizes[0] / 128;
    const int E   = in_sizes[1] / 2;
    const int ET  = E + N;
    const int R   = (ET + CH - 1) / CH;           // partition rounds
    const int NBK = (N + BW - 1) >> BSH;          // buckets (<=256)

    __hip_bfloat16* A = (__hip_bfloat16*)d_ws;        // h (bf16), N*64
    float* B       = (float*)(A + (size_t)N * 64);    // layer1 x, N*64 f32
    float* asb     = B + (size_t)N * 64;              // N
    float* adb     = asb + N;                         // N
    int*   row_ptr = (int*)(adb + N);                 // N+1
    int*   col_idx = row_ptr + (N + 1);               // ET
    int*   pbuf    = col_idx + ET;                    // ET
    int*   H       = pbuf + ET;                       // R*NBK
    int*   S2      = H + R * NBK;                     // R*NBK
    int*   tot     = S2 + R * NBK;                    // NBK
    int*   base    = tot + NBK;                       // NBK

    // W fragment buffers alias pbuf (dead after csr_build; prep runs after it)
    uintptr_t wp = ((uintptr_t)pbuf + 15) & ~(uintptr_t)15;
    unsigned short* wf1 = (unsigned short*)wp;        // 128*64 ushort = 16KB
    unsigned short* wf2 = wf1 + 128 * 64;             // 64*64 ushort = 8KB

    const int T = 256;
    const int aggBlocks  = (N + 31) / 32;
    const int nChunks    = (N + 63) / 64;
    const int gemmBlocks = nChunks < 512 ? nChunks : 512;

    // ---- radix CSR build (5 launches, LDS atomics only — R4-proven) ----
    bucket_hist_kernel<<<PGRID, T, 0, stream>>>(adj, H, E, N, R, NBK);
    scan_rounds_kernel<<<NBK, T, 0, stream>>>(H, S2, tot, R, NBK);
    scan_tot_kernel<<<1, T, 0, stream>>>(tot, base, NBK);
    partition_kernel<<<PGRID, T, 0, stream>>>(adj, S2, base, pbuf, E, N, R, NBK);
    csr_build_kernel<<<NBK, T, 0, stream>>>(base, tot, pbuf, row_ptr, col_idx, E, N, NBK);

    // ---- pack both W fragment buffers (1 launch; pbuf dead now) ----
    prep_wfrag2_kernel<<<(128 * 64 + 255) / 256, T, 0, stream>>>(W1, W2, wf1, wf2);

    // ---- layer 1 ----
    gemm_alpha_mfma<128><<<gemmBlocks, T, 0, stream>>>(
        X, wf1, a_s1, a_d1, A, asb, adb, N, nChunks);
    gat_aggregate_kernel<<<aggBlocks, T, 0, stream>>>(
        row_ptr, col_idx, asb, adb, A, b1, B, N, 1, nullptr, nullptr, nullptr);

    // ---- layer 2 + fused classifier (x into d_out tail, logits into d_out) ----
    float* out  = (float*)d_out;
    float* xout = out + (size_t)N * 16;
    gemm_alpha_mfma<64><<<gemmBlocks, T, 0, stream>>>(
        B, wf2, a_s2, a_d2, A, asb, adb, N, nChunks);
    gat_aggregate_kernel<<<aggBlocks, T, 0, stream>>>(
        row_ptr, col_idx, asb, adb, A, b2, xout, N, 0, cW, cb, out);
}

// Round 11
// 295.689 us; speedup vs baseline: 2.2036x; 1.0438x over previous
//
#include <hip/hip_runtime.h>
#include <hip/hip_bf16.h>

#define NEG_SLOPE 0.2f
#define LOG2E 1.4426950408889634f
#define BSH 9                    // 512 dst nodes per bucket
#define BW  (1 << BSH)
#define CH  4096                 // edges per partition round
#define PGRID 256                // workgroups for A0/A1

typedef short short8 __attribute__((ext_vector_type(8)));
typedef float f32x4 __attribute__((ext_vector_type(4)));

// ================= radix CSR build (no global atomics — R4-proven) =================

// A0: per-round bucket histogram. H[r*NBK + b] = #edges of round r in bucket b.
__global__ __launch_bounds__(256) void bucket_hist_kernel(
    const int* __restrict__ adj, int* __restrict__ H, int E, int N, int R, int NBK)
{
    __shared__ int hist[256];
    const int t = threadIdx.x;
    const int ET = E + N;
    for (int r = blockIdx.x; r < R; r += gridDim.x) {
        hist[t] = 0;
        __syncthreads();
        int base = r * CH;
        for (int i = 0; i < CH / 256; ++i) {
            int e = base + i * 256 + t;
            if (e >= ET) break;
            int d = (e < E) ? adj[E + e] : (e - E);
            atomicAdd(&hist[d >> BSH], 1);
        }
        __syncthreads();
        if (t < NBK) H[r * NBK + t] = hist[t];
        __syncthreads();
    }
}

// Per-bucket scan over rounds: S2[r][b] = within-bucket prefix, tot[b] = total.
__global__ __launch_bounds__(256) void scan_rounds_kernel(
    const int* __restrict__ H, int* __restrict__ S2, int* __restrict__ tot,
    int R, int NBK)
{
    __shared__ int part[256];
    const int b = blockIdx.x;
    const int t = threadIdx.x;
    const int C = (R + 255) / 256;
    int r0 = t * C, r1 = min(R, r0 + C);
    int s = 0;
    for (int r = r0; r < r1; ++r) s += H[r * NBK + b];
    part[t] = s;
    __syncthreads();
    for (int off = 1; off < 256; off <<= 1) {
        int v = (t >= off) ? part[t - off] : 0;
        __syncthreads();
        part[t] += v;
        __syncthreads();
    }
    int run = (t > 0) ? part[t - 1] : 0;
    for (int r = r0; r < r1; ++r) {
        int h = H[r * NBK + b];
        S2[r * NBK + b] = run;
        run += h;
    }
    if (t == 255) tot[b] = part[255];
}

// Exclusive scan of bucket totals -> base[b]. One block; NBK <= 256.
__global__ __launch_bounds__(256) void scan_tot_kernel(
    const int* __restrict__ tot, int* __restrict__ base, int NBK)
{
    __shared__ int s[256];
    int t = threadIdx.x;
    int v = (t < NBK) ? tot[t] : 0;
    s[t] = v;
    __syncthreads();
    for (int off = 1; off < 256; off <<= 1) {
        int u = (t >= off) ? s[t - off] : 0;
        __syncthreads();
        s[t] += u;
        __syncthreads();
    }
    if (t < NBK) base[t] = s[t] - v;
}

// A1: scatter edges into bucket-grouped pbuf at precomputed offsets.
__global__ __launch_bounds__(256) void partition_kernel(
    const int* __restrict__ adj, const int* __restrict__ S2,
    const int* __restrict__ base, int* __restrict__ pbuf,
    int E, int N, int R, int NBK)
{
    __shared__ int lcur[256];
    const int t = threadIdx.x;
    const int ET = E + N;
    for (int r = blockIdx.x; r < R; r += gridDim.x) {
        if (t < NBK) lcur[t] = base[t] + S2[r * NBK + t];
        __syncthreads();
        int b0 = r * CH;
        for (int i = 0; i < CH / 256; ++i) {
            int e = b0 + i * 256 + t;
            if (e >= ET) break;
            int s, d;
            if (e < E) { d = adj[E + e]; s = adj[e]; }
            else       { s = d = e - E; }
            int b = d >> BSH;
            int pos = atomicAdd(&lcur[b], 1);
            pbuf[pos] = (s << BSH) | (d & (BW - 1));
        }
        __syncthreads();
    }
}

// B: one WG per bucket -> row_ptr window + node-grouped col_idx (LDS atomics).
__global__ __launch_bounds__(256) void csr_build_kernel(
    const int* __restrict__ base, const int* __restrict__ tot,
    const int* __restrict__ pbuf,
    int* __restrict__ row_ptr, int* __restrict__ col_idx, int E, int N, int NBK)
{
    __shared__ int offA[BW];
    __shared__ int lcur[BW];
    const int b = blockIdx.x;
    const int t = threadIdx.x;
    const int node0 = b << BSH;
    const int nn = min(BW, N - node0);
    const int ET = E + N;
    const int segbeg = base[b];
    const int segend = segbeg + tot[b];

    offA[t] = 0; offA[t + 256] = 0;
    __syncthreads();
    for (int i = segbeg + t; i < segend; i += 256)
        atomicAdd(&offA[pbuf[i] & (BW - 1)], 1);
    __syncthreads();
    for (int off = 1; off < BW; off <<= 1) {
        int i1 = t + 256;
        int v0 = (t >= off) ? offA[t - off] : 0;
        int v1 = (i1 >= off) ? offA[i1 - off] : 0;
        __syncthreads();
        offA[t] += v0; offA[i1] += v1;
        __syncthreads();
    }
    if (t < nn) {
        int ex = t ? offA[t - 1] : 0;
        row_ptr[node0 + t] = segbeg + ex;
        lcur[t] = segbeg + ex;
    }
    int i2 = t + 256;
    if (i2 < nn) {
        int ex = offA[i2 - 1];
        row_ptr[node0 + i2] = segbeg + ex;
        lcur[i2] = segbeg + ex;
    }
    if (b == NBK - 1 && t == 0) row_ptr[N] = ET;
    __syncthreads();
    for (int i = segbeg + t; i < segend; i += 256) {
        int p = pbuf[i];
        int pos = atomicAdd(&lcur[p & (BW - 1)], 1);
        col_idx[pos] = p >> BSH;
    }
}

// ================= dense pieces =================

__device__ __forceinline__ unsigned short f2bf(float f)
{
    union { __hip_bfloat16 b; unsigned short u; } v;
    v.b = __float2bfloat16(f);
    return v.u;
}

// Pack BOTH W matrices into MFMA B-fragment order, one launch.
// frag f = s*4+t, lane l, elem i: k = 32s + 8*(l/16) + i, n = 16t + (l%16).
__global__ __launch_bounds__(256) void prep_wfrag2_kernel(
    const float* __restrict__ W1, const float* __restrict__ W2,
    unsigned short* __restrict__ wf1, unsigned short* __restrict__ wf2)
{
    int idx = blockIdx.x * 256 + threadIdx.x;
    if (idx < 128 * 64) {
        int i = idx & 7, l = (idx >> 3) & 63, f = idx >> 9;
        int s = f >> 2, tt = f & 3;
        wf1[idx] = f2bf(W1[(32 * s + 8 * (l >> 4) + i) * 64 + (16 * tt + (l & 15))]);
    }
    if (idx < 64 * 64) {
        int i = idx & 7, l = (idx >> 3) & 63, f = idx >> 9;
        int s = f >> 2, tt = f & 3;
        wf2[idx] = f2bf(W2[(32 * s + 8 * (l >> 4) + i) * 64 + (16 * tt + (l & 15))]);
    }
}

// MFMA GEMM + alpha:  h = bf16(X @ W); as[n] = (h . a_src)*log2e; ad likewise.
template<int K>
__global__ __launch_bounds__(256) void gemm_alpha_mfma(
    const float* __restrict__ X, const unsigned short* __restrict__ wf,
    const float* __restrict__ a_src, const float* __restrict__ a_dst,
    __hip_bfloat16* __restrict__ h, float* __restrict__ as_, float* __restrict__ ad_,
    int N, int nChunks)
{
    constexpr int S = K / 32;
    const int t = threadIdx.x;
    const int wave = t >> 6, lane = t & 63;
    const int g = lane >> 4, c = lane & 15;

    short8 bf[S * 4];
#pragma unroll
    for (int f = 0; f < S * 4; ++f)
        bf[f] = *(const short8*)(wf + ((size_t)(f * 64 + lane)) * 8);

    float asr[4], adr[4];
#pragma unroll
    for (int tt = 0; tt < 4; ++tt) {
        asr[tt] = a_src[16 * tt + c];
        adr[tt] = a_dst[16 * tt + c];
    }

    for (int chunk = blockIdx.x; chunk < nChunks; chunk += gridDim.x) {
        const int r0 = chunk * 64 + wave * 16;
        const int arow = r0 + c;
        const bool rv = arow < N;
        const float* xr = X + (size_t)arow * K;

        f32x4 acc[4];
#pragma unroll
        for (int tt = 0; tt < 4; ++tt) acc[tt] = (f32x4){0.f, 0.f, 0.f, 0.f};

#pragma unroll
        for (int s = 0; s < S; ++s) {
            float4 x0 = make_float4(0.f, 0.f, 0.f, 0.f);
            float4 x1 = make_float4(0.f, 0.f, 0.f, 0.f);
            if (rv) {
                const float4* p = (const float4*)(xr + 32 * s + 8 * g);
                x0 = p[0]; x1 = p[1];
            }
            float xs[8] = {x0.x, x0.y, x0.z, x0.w, x1.x, x1.y, x1.z, x1.w};
            union { short8 v; unsigned u[4]; } ah, al;
#pragma unroll
            for (int p2 = 0; p2 < 4; ++p2) {
                unsigned u0 = __float_as_uint(xs[2 * p2]);
                unsigned u1 = __float_as_uint(xs[2 * p2 + 1]);
                ah.u[p2] = (u0 >> 16) | (u1 & 0xffff0000u);
                float h0 = __uint_as_float(u0 & 0xffff0000u);
                float h1 = __uint_as_float(u1 & 0xffff0000u);
                unsigned l0 = __float_as_uint(xs[2 * p2] - h0);
                unsigned l1 = __float_as_uint(xs[2 * p2 + 1] - h1);
                al.u[p2] = (l0 >> 16) | (l1 & 0xffff0000u);
            }
#pragma unroll
            for (int tt = 0; tt < 4; ++tt) {
                acc[tt] = __builtin_amdgcn_mfma_f32_16x16x32_bf16(
                    ah.v, bf[s * 4 + tt], acc[tt], 0, 0, 0);
                acc[tt] = __builtin_amdgcn_mfma_f32_16x16x32_bf16(
                    al.v, bf[s * 4 + tt], acc[tt], 0, 0, 0);
            }
        }

#pragma unroll
        for (int i = 0; i < 4; ++i) {
            const int ri = r0 + 4 * g + i;
            float va = 0.f, vd = 0.f;
#pragma unroll
            for (int tt = 0; tt < 4; ++tt) {
                float v = acc[tt][i];
                va += v * asr[tt];
                vd += v * adr[tt];
                if (ri < N) h[(size_t)ri * 64 + 16 * tt + c] = __float2bfloat16(v);
            }
#pragma unroll
            for (int off = 8; off >= 1; off >>= 1) {
                va += __shfl_xor(va, off, 16);
                vd += __shfl_xor(vd, off, 16);
            }
            if (c == 0 && ri < N) { as_[ri] = va * LOG2E; ad_[ri] = vd * LOG2E; }
        }
    }
}

// Fused softmax+aggregate: ONE 8-LANE SUB PER NODE (8 nodes/wave), natural
// order, 2-EDGE windows — the R4-measured config (~43us/dispatch, gather-
// throughput bound). NO classifier fusion: R10 post-mortem showed the fused
// epilogue's lg[16]+cw register set spills to scratch (VGPR capped at 32,
// ~250MB scratch traffic, +36us/dispatch). Separate kernels are cheaper.
#define ACC8(u, p)                                                              \
    w = u.x; acc[0] += p * __uint_as_float(w << 16); acc[1] += p * __uint_as_float(w & 0xffff0000u); \
    w = u.y; acc[2] += p * __uint_as_float(w << 16); acc[3] += p * __uint_as_float(w & 0xffff0000u); \
    w = u.z; acc[4] += p * __uint_as_float(w << 16); acc[5] += p * __uint_as_float(w & 0xffff0000u); \
    w = u.w; acc[6] += p * __uint_as_float(w << 16); acc[7] += p * __uint_as_float(w & 0xffff0000u);

__global__ __launch_bounds__(256) void gat_aggregate_kernel(
    const int* __restrict__ row_ptr, const int* __restrict__ col_idx,
    const float* __restrict__ as_, const float* __restrict__ ad_,
    const __hip_bfloat16* __restrict__ h, const float* __restrict__ b,
    float* __restrict__ out, int N, int do_elu)
{
    const int wave = threadIdx.x >> 6, lane = threadIdx.x & 63;
    const int sub = lane >> 3, q = lane & 7;
    const int node = blockIdx.x * 32 + wave * 8 + sub;
    if (node >= N) return;
    const int beg = row_ptr[node], end = row_ptr[node + 1];
    const float ad = ad_[node];          // pre-scaled by log2e
    float acc[8] = {0.f, 0.f, 0.f, 0.f, 0.f, 0.f, 0.f, 0.f};
    float psum = 0.f;

    const char* cbp = (const char*)col_idx;
    const char* abp = (const char*)as_;
    const char* hbp = (const char*)h;
    const unsigned qb = (unsigned)q * 16u;
    unsigned w;

    unsigned co = (unsigned)beg * 4u;
    for (int i = beg; i < end; i += 2, co += 8u) {
        const bool v1 = (i + 1) < end;
        int s0 = *(const int*)(cbp + co);
        int s1 = *(const int*)(cbp + (v1 ? co + 4u : co));
        float x0 = *(const float*)(abp + ((unsigned)s0 << 2)) + ad;
        float x1 = *(const float*)(abp + ((unsigned)s1 << 2)) + ad;
        uint4 u0 = *(const uint4*)(hbp + (((unsigned)s0 << 7) + qb));
        uint4 u1 = *(const uint4*)(hbp + (((unsigned)s1 << 7) + qb));
        x0 = fmaxf(x0, NEG_SLOPE * x0);
        x1 = fmaxf(x1, NEG_SLOPE * x1);
        float p0 = __builtin_amdgcn_exp2f(x0);
        float p1 = v1 ? __builtin_amdgcn_exp2f(x1) : 0.f;
        psum += p0 + p1;
        ACC8(u0, p0)
        ACC8(u1, p1)
    }

    const float inv = 1.f / psum;
    const float* bq = b + q * 8;
    float4 b0 = *(const float4*)bq;
    float4 b1 = *(const float4*)(bq + 4);
    float v[8];
    v[0] = acc[0] * inv + b0.x; v[1] = acc[1] * inv + b0.y;
    v[2] = acc[2] * inv + b0.z; v[3] = acc[3] * inv + b0.w;
    v[4] = acc[4] * inv + b1.x; v[5] = acc[5] * inv + b1.y;
    v[6] = acc[6] * inv + b1.z; v[7] = acc[7] * inv + b1.w;
    if (do_elu) {
#pragma unroll
        for (int j = 0; j < 8; ++j)
            v[j] = v[j] > 0.f ? v[j] : (__expf(v[j]) - 1.f);
    }
    float* op = out + (size_t)node * 64 + q * 8;
    ((float4*)op)[0] = make_float4(v[0], v[1], v[2], v[3]);
    ((float4*)op)[1] = make_float4(v[4], v[5], v[6], v[7]);
}

// logits[n][c] = x[n]·cW[:,c] + cb[c]
__global__ __launch_bounds__(256) void classifier_kernel(
    const float* __restrict__ x, const float* __restrict__ cw,
    const float* __restrict__ cb, float* __restrict__ out, int N)
{
    int i = blockIdx.x * blockDim.x + threadIdx.x;
    if (i >= N * 16) return;
    int n = i >> 4, c = i & 15;
    const float4* xr = (const float4*)(x + (size_t)n * 64);
    float acc = cb[c];
#pragma unroll
    for (int j4 = 0; j4 < 16; ++j4) {
        float4 xv = xr[j4];
        acc += xv.x * cw[(j4 * 4 + 0) * 16 + c];
        acc += xv.y * cw[(j4 * 4 + 1) * 16 + c];
        acc += xv.z * cw[(j4 * 4 + 2) * 16 + c];
        acc += xv.w * cw[(j4 * 4 + 3) * 16 + c];
    }
    out[i] = acc;
}

extern "C" void kernel_launch(void* const* d_in, const int* in_sizes, int n_in,
                              void* d_out, int out_size, void* d_ws, size_t ws_size,
                              hipStream_t stream)
{
    const float* X    = (const float*)d_in[0];
    const int*   adj  = (const int*)d_in[1];
    const float* W1   = (const float*)d_in[2];
    const float* a_s1 = (const float*)d_in[3];
    const float* a_d1 = (const float*)d_in[4];
    const float* b1   = (const float*)d_in[5];
    const float* W2   = (const float*)d_in[6];
    const float* a_s2 = (const float*)d_in[7];
    const float* a_d2 = (const float*)d_in[8];
    const float* b2   = (const float*)d_in[9];
    const float* cW   = (const float*)d_in[10];
    const float* cb   = (const float*)d_in[11];

    const int N   = in_sizes[0] / 128;
    const int E   = in_sizes[1] / 2;
    const int ET  = E + N;
    const int R   = (ET + CH - 1) / CH;           // partition rounds
    const int NBK = (N + BW - 1) >> BSH;          // buckets (<=256)

    __hip_bfloat16* A = (__hip_bfloat16*)d_ws;        // h (bf16), N*64
    float* B       = (float*)(A + (size_t)N * 64);    // layer1 x, N*64 f32
    float* asb     = B + (size_t)N * 64;              // N
    float* adb     = asb + N;                         // N
    int*   row_ptr = (int*)(adb + N);                 // N+1
    int*   col_idx = row_ptr + (N + 1);               // ET
    int*   pbuf    = col_idx + ET;                    // ET
    int*   H       = pbuf + ET;                       // R*NBK
    int*   S2      = H + R * NBK;                     // R*NBK
    int*   tot     = S2 + R * NBK;                    // NBK
    int*   base    = tot + NBK;                       // NBK

    // W fragment buffers alias pbuf (dead after csr_build; prep runs after it)
    uintptr_t wp = ((uintptr_t)pbuf + 15) & ~(uintptr_t)15;
    unsigned short* wf1 = (unsigned short*)wp;        // 128*64 ushort = 16KB
    unsigned short* wf2 = wf1 + 128 * 64;             // 64*64 ushort = 8KB

    const int T = 256;
    const int aggBlocks  = (N + 31) / 32;
    const int nChunks    = (N + 63) / 64;
    const int gemmBlocks = nChunks < 512 ? nChunks : 512;

    // ---- radix CSR build (5 launches, LDS atomics only — R4-proven) ----
    bucket_hist_kernel<<<PGRID, T, 0, stream>>>(adj, H, E, N, R, NBK);
    scan_rounds_kernel<<<NBK, T, 0, stream>>>(H, S2, tot, R, NBK);
    scan_tot_kernel<<<1, T, 0, stream>>>(tot, base, NBK);
    partition_kernel<<<PGRID, T, 0, stream>>>(adj, S2, base, pbuf, E, N, R, NBK);
    csr_build_kernel<<<NBK, T, 0, stream>>>(base, tot, pbuf, row_ptr, col_idx, E, N, NBK);

    // ---- pack both W fragment buffers (1 launch; pbuf dead now) ----
    prep_wfrag2_kernel<<<(128 * 64 + 255) / 256, T, 0, stream>>>(W1, W2, wf1, wf2);

    // ---- layer 1 ----
    gemm_alpha_mfma<128><<<gemmBlocks, T, 0, stream>>>(
        X, wf1, a_s1, a_d1, A, asb, adb, N, nChunks);
    gat_aggregate_kernel<<<aggBlocks, T, 0, stream>>>(
        row_ptr, col_idx, asb, adb, A, b1, B, N, 1);

    // ---- layer 2 (x written straight into d_out tail) ----
    float* out  = (float*)d_out;
    float* xout = out + (size_t)N * 16;
    gemm_alpha_mfma<64><<<gemmBlocks, T, 0, stream>>>(
        B, wf2, a_s2, a_d2, A, asb, adb, N, nChunks);
    gat_aggregate_kernel<<<aggBlocks, T, 0, stream>>>(
        row_ptr, col_idx, asb, adb, A, b2, xout, N, 0);

    // ---- classifier ----
    classifier_kernel<<<(N * 16 + T - 1) / T, T, 0, stream>>>(
        xout, cW, cb, out, N);
}